// Round 2
// baseline (5973.674 us; speedup 1.0000x reference)
//
#include <hip/hip_runtime.h>
#include <math.h>

#define P_ 6
#define B_ 4
#define HD_ 10
#define E_ 12
#define H_ 128
#define W_ 128
#define HW_ 16384

__device__ __forceinline__ float sigm(float x){ return 1.f/(1.f+expf(-x)); }

// ---------------------------------------------------------------------------
// Kernel 1: att_dec / dp_att (written directly into d_out output slots)
// ---------------------------------------------------------------------------
__global__ __launch_bounds__(256) void attn_kernel(
    const float* __restrict__ xp, const float* __restrict__ xh,
    const float* __restrict__ w_att, const float* __restrict__ b_att,
    const float* __restrict__ w_dec, const float* __restrict__ b_dec,
    float* __restrict__ out_att, float* __restrict__ out_dp)
{
  int idx = blockIdx.x*256 + threadIdx.x;       // p*B*HW + b*HW + hw
  int hw = idx & (HW_-1);
  int pb = idx >> 14;
  int b = pb & 3;
  int p = pb >> 2;
  int half = (p>=4) ? 1 : 0;
  const float* xpb = xp + ((size_t)(p*B_+b)*HD_)*HW_ + hw;
  const float* xhb = xh + ((size_t)(half*B_+b)*HD_)*HW_ + hw;
  float da = 0.f, dd = 0.f;
  #pragma unroll
  for (int c=0;c<10;c++){
    float v = xpb[c*HW_];
    float u = xhb[c*HW_];
    da += v * w_att[p*10+c];
    dd += u * w_dec[p*20+c] + v * w_dec[p*20+10+c];
  }
  out_att[idx] = sigm(dd + b_dec[p]);
  out_dp[idx]  = sigm(da + b_att[p]);
}

// ---------------------------------------------------------------------------
// Kernel 2/4: 3x3 SAME conv, 20 in-ch -> 27 out-ch (offset+mask head).
// ---------------------------------------------------------------------------
template<bool GATHER>
__global__ __launch_bounds__(256) void conv_off_kernel(
    const float* __restrict__ xin,
    const int* __restrict__ src, const int* __restrict__ dst,
    const float* __restrict__ w_off, const float* __restrict__ b_off,
    float* __restrict__ om)
{
  __shared__ __align__(16) float s_in[20*18*18];   // 25.9 KB: 16x16 tile + halo
  __shared__ __align__(16) float s_w[20*9*28];     // 19.7 KB: [c][k][o pad 28]
  int e = blockIdx.z, b = blockIdx.y;
  int tid = threadIdx.x;
  int srcv = 0, dstv = 0;
  if (GATHER){ srcv = src[e]; dstv = dst[e]; }

  for (int i=tid; i<20*9*28; i+=256){
    int c = i/252; int r = i - c*252; int k = r/28; int o = r - k*28;
    s_w[i] = (o<27) ? w_off[(((size_t)e*27+o)*20+c)*9+k] : 0.f;
  }

  int tyi = blockIdx.x>>3, txi = blockIdx.x&7;
  int ty0 = tyi*16, tx0 = txi*16;

  for (int i=tid; i<20*324; i+=256){
    int c = i/324; int r = i - c*324; int yy = r/18; int xx = r - yy*18;
    int gy = ty0 - 1 + yy, gx = tx0 - 1 + xx;
    const float* cb;
    if (GATHER){
      int part = (c<10) ? dstv : srcv;
      int cc = (c<10) ? c : c-10;
      cb = xin + ((size_t)(part*B_+b)*HD_ + cc)*HW_;
    } else {
      cb = xin + ((size_t)(e*B_+b)*20 + c)*HW_;
    }
    float v = 0.f;
    if (gy>=0 && gy<H_ && gx>=0 && gx<W_) v = cb[gy*W_+gx];
    s_in[i] = v;
  }
  __syncthreads();

  int py = tid>>4, px = tid&15;
  float acc[28];
  #pragma unroll
  for (int o=0;o<28;o++) acc[o]=0.f;

  for (int c=0;c<20;c++){
    const float* tc = &s_in[c*324];
    #pragma unroll
    for (int k=0;k<9;k++){
      int ky=k/3, kx=k-ky*3;
      float v = tc[(py+ky)*18 + (px+kx)];
      const float4* wp = (const float4*)&s_w[(c*9+k)*28];   // wave-uniform broadcast
      #pragma unroll
      for (int j=0;j<7;j++){
        float4 w4 = wp[j];
        acc[4*j+0] += v*w4.x;
        acc[4*j+1] += v*w4.y;
        acc[4*j+2] += v*w4.z;
        acc[4*j+3] += v*w4.w;
      }
    }
  }

  int hw = (ty0+py)*W_ + tx0+px;
  float* ob = om + ((size_t)(e*B_+b)*27)*HW_ + hw;
  #pragma unroll
  for (int o=0;o<27;o++) ob[o*HW_] = acc[o] + b_off[e*27+o];
}

// ---------------------------------------------------------------------------
// Kernel 3/5: deformable sampling + per-tap 20xCO einsum + BN + ReLU.
// LDS-tiled sampling: 32x8 pixel tile + halo 2 (12x36 per channel, zero-padded
// outside the image). Offsets are conv outputs with 0.01-scale weights, so
// |off|<1 ~always -> samples hit the staged tile; a per-lane global fallback
// branch (execz-skipped when unused) keeps arbitrary offsets correct.
// LAYER2 additionally folds a2b = (1-dp[src]) * edge_out * dp[dst].
// ---------------------------------------------------------------------------
#define TR_ 12     // staged rows  (8 + 2*2 halo)
#define TC_ 36     // staged cols  (32 + 2*2 halo)
template<int CO, int COP, bool LAYER2>
__global__ __launch_bounds__(256, 3) void deform_kernel(
    const float* __restrict__ xin,      // layer1: xp (gathered); layer2: hbuf
    const float* __restrict__ om,
    const float* __restrict__ w, const float* __restrict__ sc, const float* __restrict__ bi,
    const int* __restrict__ src, const int* __restrict__ dst,
    const float* __restrict__ dp,       // dp_att (layer2 only)
    float* __restrict__ out)
{
  __shared__ __align__(16) float s_w[9*20*COP];       // [t][c][o pad COP]
  __shared__ __align__(16) float s_tile[20*TR_*TC_];  // 34.6 KB
  int e = blockIdx.z, b = blockIdx.y;
  int tid = threadIdx.x;
  int srcv = src[e], dstv = dst[e];

  const float* base_lo; const float* base_hi;
  if (!LAYER2){
    base_lo = xin + ((size_t)(dstv*B_+b)*HD_)*HW_;   // channels 0..9
    base_hi = xin + ((size_t)(srcv*B_+b)*HD_)*HW_;   // channels 10..19
  } else {
    base_lo = xin + ((size_t)(e*B_+b)*20)*HW_;
    base_hi = base_lo + 10*HW_;
  }

  for (int i=tid; i<9*20*COP; i+=256){
    int k = i/(20*COP); int r = i - k*(20*COP); int c = r/COP; int o = r - c*COP;
    s_w[i] = (o<CO) ? w[(((size_t)e*CO+o)*20+c)*9+k] : 0.f;
  }

  int tyi = blockIdx.x>>2, txi = blockIdx.x&3;   // 16 x 4 tiles of 8x32
  int ty0 = tyi*8, tx0 = txi*32;

  // stage 20ch x 12x36 tile, zero outside image
  for (int i=tid; i<20*TR_*TC_; i+=256){
    int c = i/(TR_*TC_); int r = i - c*(TR_*TC_); int yy = r/TC_; int xx = r - yy*TC_;
    int gy = ty0 - 2 + yy, gx = tx0 - 2 + xx;
    const float* cb = (c<10) ? (base_lo + c*HW_) : (base_hi + (c-10)*HW_);
    float vv = 0.f;
    if ((unsigned)gy < H_ && (unsigned)gx < W_) vv = cb[gy*W_+gx];
    s_tile[i] = vv;
  }
  __syncthreads();

  int py = tid>>5, px = tid&31;
  int h = ty0+py, wc = tx0+px;
  int hw = h*W_ + wc;
  const float* omb = om + ((size_t)(e*B_+b)*27)*HW_ + hw;

  float acc[COP];
  #pragma unroll
  for (int o=0;o<COP;o++) acc[o]=0.f;

  #pragma unroll 3
  for (int t=0;t<9;t++){
    float offy = omb[(2*t)*HW_];
    float offx = omb[(2*t+1)*HW_];
    float m = sigm(omb[(18+t)*HW_]);
    float pyf = (float)(h + t/3 - 1) + offy;
    float pxf = (float)(wc + t%3 - 1) + offx;
    float y0f = floorf(pyf), x0f = floorf(pxf);
    float wy = pyf - y0f, wx = pxf - x0f;
    int y0 = (int)y0f, x0 = (int)x0f;
    // bilinear corner weights with mask folded in
    float w00 = (1.f-wy)*(1.f-wx)*m;
    float w01 = (1.f-wy)*wx     *m;
    float w10 = wy     *(1.f-wx)*m;
    float w11 = wy     *wx      *m;

    int ly = y0 - ty0 + 2, lx = x0 - tx0 + 2;
    bool inTile = ((unsigned)ly <= (unsigned)(TR_-2)) & ((unsigned)lx <= (unsigned)(TC_-2));

    float v[20];
    if (inTile){
      // out-of-image texels staged as 0 -> validity handled for free
      const float* tb = s_tile + ly*TC_ + lx;
      #pragma unroll
      for (int c=0;c<20;c++){
        const float* tc = tb + c*(TR_*TC_);
        v[c] = w00*tc[0] + w01*tc[1] + w10*tc[TC_] + w11*tc[TC_+1];
      }
    } else {
      int y1 = y0+1, x1 = x0+1;
      float vy0 = (y0>=0 && y0<H_) ? 1.f : 0.f;
      float vy1 = (y1>=0 && y1<H_) ? 1.f : 0.f;
      float vx0 = (x0>=0 && x0<W_) ? 1.f : 0.f;
      float vx1 = (x1>=0 && x1<W_) ? 1.f : 0.f;
      float g00 = w00*vy0*vx0, g01 = w01*vy0*vx1;
      float g10 = w10*vy1*vx0, g11 = w11*vy1*vx1;
      int y0c = min(max(y0,0),H_-1), y1c = min(max(y1,0),H_-1);
      int x0c = min(max(x0,0),W_-1), x1c = min(max(x1,0),W_-1);
      int i00 = y0c*W_+x0c, i01 = y0c*W_+x1c, i10 = y1c*W_+x0c, i11 = y1c*W_+x1c;
      #pragma unroll
      for (int c=0;c<20;c++){
        const float* pc = (c<10) ? (base_lo + c*HW_) : (base_hi + (c-10)*HW_);
        v[c] = g00*pc[i00] + g01*pc[i01] + g10*pc[i10] + g11*pc[i11];
      }
    }

    #pragma unroll
    for (int c=0;c<20;c++){
      float vv = v[c];
      const float4* wp = (const float4*)&s_w[(t*20+c)*COP];
      #pragma unroll
      for (int j=0;j<COP/4;j++){
        float4 w4 = wp[j];
        acc[4*j+0] += vv*w4.x;
        acc[4*j+1] += vv*w4.y;
        acc[4*j+2] += vv*w4.z;
        acc[4*j+3] += vv*w4.w;
      }
    }
  }

  float dfac = 1.f;
  if (LAYER2){
    float ds = dp[((size_t)srcv*B_+b)*HW_ + hw];
    float dd = dp[((size_t)dstv*B_+b)*HW_ + hw];
    dfac = (1.f-ds)*dd;
  }

  float* ob = out + ((size_t)(e*B_+b)*CO)*HW_ + hw;
  #pragma unroll
  for (int o=0;o<CO;o++){
    float r = acc[o]*sc[e*CO+o] + bi[e*CO+o];
    r = fmaxf(r, 0.f);
    if (LAYER2) r *= dfac;
    ob[o*HW_] = r;
  }
}

// ---------------------------------------------------------------------------
// Kernel 6: segment_max over incoming edges + xhp + update matvec + residual
// ---------------------------------------------------------------------------
__global__ __launch_bounds__(256) void update_kernel(
    const float* __restrict__ xp, const float* __restrict__ xh,
    const float* __restrict__ a2b, const int* __restrict__ dst,
    const float* __restrict__ w_u, const float* __restrict__ b_u,
    const float* __restrict__ att_dec, float* __restrict__ out)
{
  __shared__ __align__(16) float s_wu[30*12];   // [c][d pad 12]
  int p = blockIdx.z, b = blockIdx.y;
  int tid = threadIdx.x;
  for (int i=tid; i<360; i+=256){
    int c = i/12; int d = i - c*12;
    s_wu[i] = (d<10) ? w_u[((size_t)p*10+d)*30+c] : 0.f;
  }
  __syncthreads();

  int tyi = blockIdx.x>>3, txi = blockIdx.x&7;
  int py = tid>>4, px = tid&15;
  int hw = (tyi*16+py)*W_ + txi*16+px;
  int half = (p>=4) ? 1 : 0;
  const float* xpb = xp + ((size_t)(p*B_+b)*HD_)*HW_ + hw;
  const float* xhb = xh + ((size_t)(half*B_+b)*HD_)*HW_ + hw;
  float ad = att_dec[((size_t)p*B_+b)*HW_ + hw];

  float in[30];
  #pragma unroll
  for (int c=0;c<10;c++) in[c] = xpb[c*HW_];
  #pragma unroll
  for (int c=0;c<10;c++) in[10+c] = -INFINITY;
  for (int e=0;e<E_;e++){
    if (dst[e]==p){                               // block-uniform branch
      const float* ab = a2b + ((size_t)(e*B_+b)*HD_)*HW_ + hw;
      #pragma unroll
      for (int c=0;c<10;c++) in[10+c] = fmaxf(in[10+c], ab[c*HW_]);
    }
  }
  #pragma unroll
  for (int c=0;c<10;c++) in[20+c] = ad * xhb[c*HW_];

  float acc[12];
  #pragma unroll
  for (int o=0;o<12;o++) acc[o]=0.f;
  #pragma unroll
  for (int c=0;c<30;c++){
    float v = in[c];
    const float4* wp = (const float4*)&s_wu[c*12];
    #pragma unroll
    for (int j=0;j<3;j++){
      float4 w4 = wp[j];
      acc[4*j+0]+=v*w4.x; acc[4*j+1]+=v*w4.y; acc[4*j+2]+=v*w4.z; acc[4*j+3]+=v*w4.w;
    }
  }

  float* ob = out + ((size_t)(p*B_+b)*HD_)*HW_ + hw;
  #pragma unroll
  for (int o=0;o<10;o++){
    float r = acc[o] + b_u[p*10+o];
    ob[o*HW_] = in[o] + fmaxf(r, 0.f);
  }
}

// ---------------------------------------------------------------------------
extern "C" void kernel_launch(void* const* d_in, const int* in_sizes, int n_in,
                              void* d_out, int out_size, void* d_ws, size_t ws_size,
                              hipStream_t stream)
{
  (void)in_sizes; (void)n_in; (void)out_size; (void)ws_size;
  // d_in[0] = p_fea (unused by the reference forward)
  const float* xp     = (const float*)d_in[1];
  const float* xh     = (const float*)d_in[2];
  const int*   src    = (const int*)d_in[3];
  const int*   dst    = (const int*)d_in[4];
  const float* w_off1 = (const float*)d_in[5];
  const float* b_off1 = (const float*)d_in[6];
  const float* w1     = (const float*)d_in[7];
  const float* s1     = (const float*)d_in[8];
  const float* bb1    = (const float*)d_in[9];
  const float* w_off2 = (const float*)d_in[10];
  const float* b_off2 = (const float*)d_in[11];
  const float* w2     = (const float*)d_in[12];
  const float* s2     = (const float*)d_in[13];
  const float* bb2    = (const float*)d_in[14];
  const float* w_att  = (const float*)d_in[15];
  const float* b_att  = (const float*)d_in[16];
  const float* w_dec  = (const float*)d_in[17];
  const float* b_dec  = (const float*)d_in[18];
  const float* w_u    = (const float*)d_in[19];
  const float* b_u    = (const float*)d_in[20];

  float* out_xp  = (float*)d_out;                                   // (6,4,10,128,128)
  float* out_att = out_xp + (size_t)P_*B_*HD_*HW_;                  // (6,4,1,128,128)
  float* out_dp  = out_att + (size_t)P_*B_*HW_;                     // (6,4,1,128,128)

  float* om   = (float*)d_ws;                       // E*B*27*HW  (85 MB, reused)
  float* hbuf = om   + (size_t)E_*B_*27*HW_;        // E*B*20*HW  (63 MB)
  float* a2b  = hbuf + (size_t)E_*B_*20*HW_;        // E*B*10*HW  (31 MB)

  dim3 blk(256);
  attn_kernel<<<(P_*B_*HW_)/256, blk, 0, stream>>>(xp, xh, w_att, b_att, w_dec, b_dec, out_att, out_dp);

  dim3 ge(64, B_, E_);
  conv_off_kernel<true ><<<ge, blk, 0, stream>>>(xp,   src, dst, w_off1, b_off1, om);
  deform_kernel<20,20,false><<<ge, blk, 0, stream>>>(xp,   om, w1, s1, bb1, src, dst, nullptr, hbuf);
  conv_off_kernel<false><<<ge, blk, 0, stream>>>(hbuf, src, dst, w_off2, b_off2, om);
  deform_kernel<10,12,true ><<<ge, blk, 0, stream>>>(hbuf, om, w2, s2, bb2, src, dst, out_dp, a2b);

  dim3 gu(64, B_, P_);
  update_kernel<<<gu, blk, 0, stream>>>(xp, xh, a2b, dst, w_u, b_u, out_att, out_xp);
}

// Round 3
// 1158.643 us; speedup vs baseline: 5.1557x; 5.1557x over previous
//
#include <hip/hip_runtime.h>
#include <math.h>

#define P_ 6
#define B_ 4
#define HD_ 10
#define E_ 12
#define H_ 128
#define W_ 128
#define HW_ 16384

__device__ __forceinline__ float sigm(float x){ return 1.f/(1.f+expf(-x)); }

// ---------------------------------------------------------------------------
// Kernel 1: att_dec / dp_att (written directly into d_out output slots)
// ---------------------------------------------------------------------------
__global__ __launch_bounds__(256) void attn_kernel(
    const float* __restrict__ xp, const float* __restrict__ xh,
    const float* __restrict__ w_att, const float* __restrict__ b_att,
    const float* __restrict__ w_dec, const float* __restrict__ b_dec,
    float* __restrict__ out_att, float* __restrict__ out_dp)
{
  int idx = blockIdx.x*256 + threadIdx.x;       // p*B*HW + b*HW + hw
  int hw = idx & (HW_-1);
  int pb = idx >> 14;
  int b = pb & 3;
  int p = pb >> 2;
  int half = (p>=4) ? 1 : 0;
  const float* xpb = xp + ((size_t)(p*B_+b)*HD_)*HW_ + hw;
  const float* xhb = xh + ((size_t)(half*B_+b)*HD_)*HW_ + hw;
  float da = 0.f, dd = 0.f;
  #pragma unroll
  for (int c=0;c<10;c++){
    float v = xpb[c*HW_];
    float u = xhb[c*HW_];
    da += v * w_att[p*10+c];
    dd += u * w_dec[p*20+c] + v * w_dec[p*20+10+c];
  }
  out_att[idx] = sigm(dd + b_dec[p]);
  out_dp[idx]  = sigm(da + b_att[p]);
}

// ---------------------------------------------------------------------------
// Kernel 2/4: 3x3 SAME conv, 20 in-ch -> 27 out-ch (offset+mask head).
// ---------------------------------------------------------------------------
template<bool GATHER>
__global__ __launch_bounds__(256) void conv_off_kernel(
    const float* __restrict__ xin,
    const int* __restrict__ src, const int* __restrict__ dst,
    const float* __restrict__ w_off, const float* __restrict__ b_off,
    float* __restrict__ om)
{
  __shared__ __align__(16) float s_in[20*18*18];   // 25.9 KB: 16x16 tile + halo
  __shared__ __align__(16) float s_w[20*9*28];     // 19.7 KB: [c][k][o pad 28]
  int e = blockIdx.z, b = blockIdx.y;
  int tid = threadIdx.x;
  int srcv = 0, dstv = 0;
  if (GATHER){ srcv = src[e]; dstv = dst[e]; }

  for (int i=tid; i<20*9*28; i+=256){
    int c = i/252; int r = i - c*252; int k = r/28; int o = r - k*28;
    s_w[i] = (o<27) ? w_off[(((size_t)e*27+o)*20+c)*9+k] : 0.f;
  }

  int tyi = blockIdx.x>>3, txi = blockIdx.x&7;
  int ty0 = tyi*16, tx0 = txi*16;

  for (int i=tid; i<20*324; i+=256){
    int c = i/324; int r = i - c*324; int yy = r/18; int xx = r - yy*18;
    int gy = ty0 - 1 + yy, gx = tx0 - 1 + xx;
    const float* cb;
    if (GATHER){
      int part = (c<10) ? dstv : srcv;
      int cc = (c<10) ? c : c-10;
      cb = xin + ((size_t)(part*B_+b)*HD_ + cc)*HW_;
    } else {
      cb = xin + ((size_t)(e*B_+b)*20 + c)*HW_;
    }
    float v = 0.f;
    if (gy>=0 && gy<H_ && gx>=0 && gx<W_) v = cb[gy*W_+gx];
    s_in[i] = v;
  }
  __syncthreads();

  int py = tid>>4, px = tid&15;
  float acc[28];
  #pragma unroll
  for (int o=0;o<28;o++) acc[o]=0.f;

  for (int c=0;c<20;c++){
    const float* tc = &s_in[c*324];
    #pragma unroll
    for (int k=0;k<9;k++){
      int ky=k/3, kx=k-ky*3;
      float v = tc[(py+ky)*18 + (px+kx)];
      const float4* wp = (const float4*)&s_w[(c*9+k)*28];   // wave-uniform broadcast
      #pragma unroll
      for (int j=0;j<7;j++){
        float4 w4 = wp[j];
        acc[4*j+0] += v*w4.x;
        acc[4*j+1] += v*w4.y;
        acc[4*j+2] += v*w4.z;
        acc[4*j+3] += v*w4.w;
      }
    }
  }

  int hw = (ty0+py)*W_ + tx0+px;
  float* ob = om + ((size_t)(e*B_+b)*27)*HW_ + hw;
  #pragma unroll
  for (int o=0;o<27;o++) ob[o*HW_] = acc[o] + b_off[e*27+o];
}

// ---------------------------------------------------------------------------
// Kernel 3/5: deformable sampling + per-tap 20xCO einsum + BN + ReLU.
// LDS-tiled sampling, 8x32 pixel tile + halo 2 (12x36/channel, zero-padded).
// The in-tile test is voted wave-uniform via __all() -> scalar branch, so the
// rare global-gather fallback is execz-skipped and can't be if-converted.
// No v[] array: each sample is consumed immediately (keeps VGPRs low).
// LAYER2 additionally folds a2b = (1-dp[src]) * edge_out * dp[dst].
// ---------------------------------------------------------------------------
#define TR_ 12     // staged rows  (8 + 2*2 halo)
#define TC_ 36     // staged cols  (32 + 2*2 halo)
template<int CO, int COP, bool LAYER2>
__global__ __launch_bounds__(256) void deform_kernel(
    const float* __restrict__ xin,      // layer1: xp (gathered); layer2: hbuf
    const float* __restrict__ om,
    const float* __restrict__ w, const float* __restrict__ sc, const float* __restrict__ bi,
    const int* __restrict__ src, const int* __restrict__ dst,
    const float* __restrict__ dp,       // dp_att (layer2 only)
    float* __restrict__ out)
{
  __shared__ __align__(16) float s_w[9*20*COP];       // [t][c][o pad COP]
  __shared__ __align__(16) float s_tile[20*TR_*TC_];  // 34.6 KB
  int e = blockIdx.z, b = blockIdx.y;
  int tid = threadIdx.x;
  int srcv = src[e], dstv = dst[e];

  const float* base_lo; const float* base_hi;
  if (!LAYER2){
    base_lo = xin + ((size_t)(dstv*B_+b)*HD_)*HW_;   // channels 0..9
    base_hi = xin + ((size_t)(srcv*B_+b)*HD_)*HW_;   // channels 10..19
  } else {
    base_lo = xin + ((size_t)(e*B_+b)*20)*HW_;
    base_hi = base_lo + 10*HW_;
  }

  for (int i=tid; i<9*20*COP; i+=256){
    int k = i/(20*COP); int r = i - k*(20*COP); int c = r/COP; int o = r - c*COP;
    s_w[i] = (o<CO) ? w[(((size_t)e*CO+o)*20+c)*9+k] : 0.f;
  }

  int tyi = blockIdx.x>>2, txi = blockIdx.x&3;   // 16 x 4 tiles of 8x32
  int ty0 = tyi*8, tx0 = txi*32;

  // stage 20ch x 12x36 tile, zero outside image
  for (int i=tid; i<20*TR_*TC_; i+=256){
    int c = i/(TR_*TC_); int r = i - c*(TR_*TC_); int yy = r/TC_; int xx = r - yy*TC_;
    int gy = ty0 - 2 + yy, gx = tx0 - 2 + xx;
    const float* cb = (c<10) ? (base_lo + c*HW_) : (base_hi + (c-10)*HW_);
    float vv = 0.f;
    if ((unsigned)gy < H_ && (unsigned)gx < W_) vv = cb[gy*W_+gx];
    s_tile[i] = vv;
  }
  __syncthreads();

  int py = tid>>5, px = tid&31;
  int h = ty0+py, wc = tx0+px;
  int hw = h*W_ + wc;
  const float* omb = om + ((size_t)(e*B_+b)*27)*HW_ + hw;

  float acc[COP];
  #pragma unroll
  for (int o=0;o<COP;o++) acc[o]=0.f;

  #pragma unroll 1
  for (int t=0;t<9;t++){
    float offy = omb[(2*t)*HW_];
    float offx = omb[(2*t+1)*HW_];
    float m = sigm(omb[(18+t)*HW_]);
    int ki = t/3, kj = t - ki*3;
    float pyf = (float)(h + ki - 1) + offy;
    float pxf = (float)(wc + kj - 1) + offx;
    float y0f = floorf(pyf), x0f = floorf(pxf);
    float wy = pyf - y0f, wx = pxf - x0f;
    int y0 = (int)y0f, x0 = (int)x0f;
    // bilinear corner weights with mask folded in
    float w00 = (1.f-wy)*(1.f-wx)*m;
    float w01 = (1.f-wy)*wx     *m;
    float w10 = wy     *(1.f-wx)*m;
    float w11 = wy     *wx      *m;

    int ly = y0 - ty0 + 2, lx = x0 - tx0 + 2;
    bool inTile = ((unsigned)ly <= (unsigned)(TR_-2)) & ((unsigned)lx <= (unsigned)(TC_-2));

    if (__all(inTile)) {
      // fast path (taken ~always): out-of-image texels staged as 0
      const float* tb = s_tile + ly*TC_ + lx;
      #pragma unroll
      for (int c=0;c<20;c++){
        const float* tc = tb + c*(TR_*TC_);
        float vv = w00*tc[0] + w01*tc[1] + w10*tc[TC_] + w11*tc[TC_+1];
        const float4* wp = (const float4*)&s_w[(t*20+c)*COP];
        #pragma unroll
        for (int j=0;j<COP/4;j++){
          float4 w4 = wp[j];
          acc[4*j+0] += vv*w4.x;
          acc[4*j+1] += vv*w4.y;
          acc[4*j+2] += vv*w4.z;
          acc[4*j+3] += vv*w4.w;
        }
      }
    } else {
      // rare wave-uniform fallback: full global gather with validity masks
      int y1 = y0+1, x1 = x0+1;
      float vy0 = (y0>=0 && y0<H_) ? 1.f : 0.f;
      float vy1 = (y1>=0 && y1<H_) ? 1.f : 0.f;
      float vx0 = (x0>=0 && x0<W_) ? 1.f : 0.f;
      float vx1 = (x1>=0 && x1<W_) ? 1.f : 0.f;
      float g00 = w00*vy0*vx0, g01 = w01*vy0*vx1;
      float g10 = w10*vy1*vx0, g11 = w11*vy1*vx1;
      int y0c = min(max(y0,0),H_-1), y1c = min(max(y1,0),H_-1);
      int x0c = min(max(x0,0),W_-1), x1c = min(max(x1,0),W_-1);
      int i00 = y0c*W_+x0c, i01 = y0c*W_+x1c, i10 = y1c*W_+x0c, i11 = y1c*W_+x1c;
      #pragma unroll
      for (int c=0;c<20;c++){
        const float* pc = (c<10) ? (base_lo + c*HW_) : (base_hi + (c-10)*HW_);
        float vv = g00*pc[i00] + g01*pc[i01] + g10*pc[i10] + g11*pc[i11];
        const float4* wp = (const float4*)&s_w[(t*20+c)*COP];
        #pragma unroll
        for (int j=0;j<COP/4;j++){
          float4 w4 = wp[j];
          acc[4*j+0] += vv*w4.x;
          acc[4*j+1] += vv*w4.y;
          acc[4*j+2] += vv*w4.z;
          acc[4*j+3] += vv*w4.w;
        }
      }
    }
  }

  float dfac = 1.f;
  if (LAYER2){
    float ds = dp[((size_t)srcv*B_+b)*HW_ + hw];
    float dd = dp[((size_t)dstv*B_+b)*HW_ + hw];
    dfac = (1.f-ds)*dd;
  }

  float* ob = out + ((size_t)(e*B_+b)*CO)*HW_ + hw;
  #pragma unroll
  for (int o=0;o<CO;o++){
    float r = acc[o]*sc[e*CO+o] + bi[e*CO+o];
    r = fmaxf(r, 0.f);
    if (LAYER2) r *= dfac;
    ob[o*HW_] = r;
  }
}

// ---------------------------------------------------------------------------
// Kernel 6: segment_max over incoming edges + xhp + update matvec + residual
// ---------------------------------------------------------------------------
__global__ __launch_bounds__(256) void update_kernel(
    const float* __restrict__ xp, const float* __restrict__ xh,
    const float* __restrict__ a2b, const int* __restrict__ dst,
    const float* __restrict__ w_u, const float* __restrict__ b_u,
    const float* __restrict__ att_dec, float* __restrict__ out)
{
  __shared__ __align__(16) float s_wu[30*12];   // [c][d pad 12]
  int p = blockIdx.z, b = blockIdx.y;
  int tid = threadIdx.x;
  for (int i=tid; i<360; i+=256){
    int c = i/12; int d = i - c*12;
    s_wu[i] = (d<10) ? w_u[((size_t)p*10+d)*30+c] : 0.f;
  }
  __syncthreads();

  int tyi = blockIdx.x>>3, txi = blockIdx.x&7;
  int py = tid>>4, px = tid&15;
  int hw = (tyi*16+py)*W_ + txi*16+px;
  int half = (p>=4) ? 1 : 0;
  const float* xpb = xp + ((size_t)(p*B_+b)*HD_)*HW_ + hw;
  const float* xhb = xh + ((size_t)(half*B_+b)*HD_)*HW_ + hw;
  float ad = att_dec[((size_t)p*B_+b)*HW_ + hw];

  float in[30];
  #pragma unroll
  for (int c=0;c<10;c++) in[c] = xpb[c*HW_];
  #pragma unroll
  for (int c=0;c<10;c++) in[10+c] = -INFINITY;
  for (int e=0;e<E_;e++){
    if (dst[e]==p){                               // block-uniform branch
      const float* ab = a2b + ((size_t)(e*B_+b)*HD_)*HW_ + hw;
      #pragma unroll
      for (int c=0;c<10;c++) in[10+c] = fmaxf(in[10+c], ab[c*HW_]);
    }
  }
  #pragma unroll
  for (int c=0;c<10;c++) in[20+c] = ad * xhb[c*HW_];

  float acc[12];
  #pragma unroll
  for (int o=0;o<12;o++) acc[o]=0.f;
  #pragma unroll
  for (int c=0;c<30;c++){
    float v = in[c];
    const float4* wp = (const float4*)&s_wu[c*12];
    #pragma unroll
    for (int j=0;j<3;j++){
      float4 w4 = wp[j];
      acc[4*j+0]+=v*w4.x; acc[4*j+1]+=v*w4.y; acc[4*j+2]+=v*w4.z; acc[4*j+3]+=v*w4.w;
    }
  }

  float* ob = out + ((size_t)(p*B_+b)*HD_)*HW_ + hw;
  #pragma unroll
  for (int o=0;o<10;o++){
    float r = acc[o] + b_u[p*10+o];
    ob[o*HW_] = in[o] + fmaxf(r, 0.f);
  }
}

// ---------------------------------------------------------------------------
extern "C" void kernel_launch(void* const* d_in, const int* in_sizes, int n_in,
                              void* d_out, int out_size, void* d_ws, size_t ws_size,
                              hipStream_t stream)
{
  (void)in_sizes; (void)n_in; (void)out_size; (void)ws_size;
  // d_in[0] = p_fea (unused by the reference forward)
  const float* xp     = (const float*)d_in[1];
  const float* xh     = (const float*)d_in[2];
  const int*   src    = (const int*)d_in[3];
  const int*   dst    = (const int*)d_in[4];
  const float* w_off1 = (const float*)d_in[5];
  const float* b_off1 = (const float*)d_in[6];
  const float* w1     = (const float*)d_in[7];
  const float* s1     = (const float*)d_in[8];
  const float* bb1    = (const float*)d_in[9];
  const float* w_off2 = (const float*)d_in[10];
  const float* b_off2 = (const float*)d_in[11];
  const float* w2     = (const float*)d_in[12];
  const float* s2     = (const float*)d_in[13];
  const float* bb2    = (const float*)d_in[14];
  const float* w_att  = (const float*)d_in[15];
  const float* b_att  = (const float*)d_in[16];
  const float* w_dec  = (const float*)d_in[17];
  const float* b_dec  = (const float*)d_in[18];
  const float* w_u    = (const float*)d_in[19];
  const float* b_u    = (const float*)d_in[20];

  float* out_xp  = (float*)d_out;                                   // (6,4,10,128,128)
  float* out_att = out_xp + (size_t)P_*B_*HD_*HW_;                  // (6,4,1,128,128)
  float* out_dp  = out_att + (size_t)P_*B_*HW_;                     // (6,4,1,128,128)

  float* om   = (float*)d_ws;                       // E*B*27*HW  (85 MB, reused)
  float* hbuf = om   + (size_t)E_*B_*27*HW_;        // E*B*20*HW  (63 MB)
  float* a2b  = hbuf + (size_t)E_*B_*20*HW_;        // E*B*10*HW  (31 MB)

  dim3 blk(256);
  attn_kernel<<<(P_*B_*HW_)/256, blk, 0, stream>>>(xp, xh, w_att, b_att, w_dec, b_dec, out_att, out_dp);

  dim3 ge(64, B_, E_);
  conv_off_kernel<true ><<<ge, blk, 0, stream>>>(xp,   src, dst, w_off1, b_off1, om);
  deform_kernel<20,20,false><<<ge, blk, 0, stream>>>(xp,   om, w1, s1, bb1, src, dst, nullptr, hbuf);
  conv_off_kernel<false><<<ge, blk, 0, stream>>>(hbuf, src, dst, w_off2, b_off2, om);
  deform_kernel<10,12,true ><<<ge, blk, 0, stream>>>(hbuf, om, w2, s2, bb2, src, dst, out_dp, a2b);

  dim3 gu(64, B_, P_);
  update_kernel<<<gu, blk, 0, stream>>>(xp, xh, a2b, dst, w_u, b_u, out_att, out_xp);
}